// Round 2
// baseline (92.755 us; speedup 1.0000x reference)
//
#include <hip/hip_runtime.h>

// z: [32,64,32,32] fp32, codebook: [1024,64] fp32
#define C_DIM   64
#define K_CODES 1024
#define HW      1024
#define CHW     (C_DIM * HW)             // 65536
#define N_TOTAL 32768
#define CODES_ELEMS 2097152

#define THREADS 512                      // 8 waves: ktl = w&3 (k-split), nt = w>>2 (n-tile)
#define NBLK    64
#define NGROUPS 8

typedef _Float16 half8  __attribute__((ext_vector_type(8)));
typedef float    f32x16 __attribute__((ext_vector_type(16)));

#define WS_A_ELEMS 16384                 // half8 count: 256 KB A-frags

__device__ __forceinline__ bool better(float k1, int i1, float k2, int i2) {
    return (k1 > k2) || (k1 == k2 && i1 < i2);
}
__device__ __forceinline__ void merge2(float& bk, int& bi, float& sk, int& si,
                                       float obk, int obi, float osk, int osi) {
    if (better(obk, obi, bk, bi)) {
        float nsk; int nsi;
        if (better(bk, bi, osk, osi)) { nsk = bk; nsi = bi; } else { nsk = osk; nsi = osi; }
        bk = obk; bi = obi; sk = nsk; si = nsi;
    } else {
        if (better(obk, obi, sk, si)) { sk = obk; si = obi; }
    }
}

// async global->LDS, 16B per lane. LDS dest is wave-uniform base + lane*16 (m104).
__device__ __forceinline__ void gload_lds16(const void* g, void* l) {
    __builtin_amdgcn_global_load_lds(
        (const __attribute__((address_space(1))) unsigned int*)g,
        (__attribute__((address_space(3))) unsigned int*)l, 16, 0, 0);
}

// One-shot prep: blocks 0..31 -> hi/lo fp16 A-fragment layout; block 32 -> cnorm.
// wsA layout is linear per k-group: group g occupies bytes [g*32768, (g+1)*32768)
// — exactly the contiguous order global_load_lds needs.
__global__ void prep_kernel(const float* __restrict__ cb, half8* __restrict__ wsA,
                            float* __restrict__ wsCn) {
    if (blockIdx.x < 32) {
        const int tid = blockIdx.x * 256 + threadIdx.x;   // 0..8191
        const int kt = tid >> 8, q = (tid >> 6) & 3, l = tid & 63;
        const int k  = kt * 32 + (l & 31);
        const int c0 = q * 16 + (l >> 5) * 8;
        const float4* p = (const float4*)(cb + k * C_DIM + c0);
        float4 f0 = p[0], f1 = p[1];
        float v[8] = {f0.x,f0.y,f0.z,f0.w,f1.x,f1.y,f1.z,f1.w};
        half8 h8, l8;
#pragma unroll
        for (int j = 0; j < 8; ++j) {
            _Float16 hh = (_Float16)v[j];
            _Float16 ll = (_Float16)(v[j] - (float)hh);
            h8[j] = hh; l8[j] = ll;
        }
        wsA[((kt * 4 + q) * 2 + 0) * 64 + l] = h8;
        wsA[((kt * 4 + q) * 2 + 1) * 64 + l] = l8;
    } else {
#pragma unroll
        for (int rep = 0; rep < 4; ++rep) {
            const int k = threadIdx.x * 4 + rep;
            const float4* row = (const float4*)(cb + k * C_DIM);
            float r[8];
            {
                float4 f0 = row[0], f1 = row[1];
                float v[8] = {f0.x,f0.y,f0.z,f0.w,f1.x,f1.y,f1.z,f1.w};
#pragma unroll
                for (int j = 0; j < 8; ++j) r[j] = v[j]*v[j];
            }
#pragma unroll
            for (int i = 2; i < 16; i += 2) {
                float4 f0 = row[i], f1 = row[i+1];
                float v[8] = {f0.x,f0.y,f0.z,f0.w,f1.x,f1.y,f1.z,f1.w};
#pragma unroll
                for (int j = 0; j < 8; ++j) r[j] = fmaf(v[j], v[j], r[j]);
            }
            wsCn[k] = ((r[0]+r[1])+(r[2]+r[3])) + ((r[4]+r[5])+(r[6]+r[7]));
        }
    }
}

__launch_bounds__(THREADS, 4)
__global__ void vq_kernel(const float* __restrict__ z, const float* __restrict__ cb,
                          const half8* __restrict__ wsA, const float* __restrict__ wsCn,
                          float* __restrict__ out) {
    // A-fragment double buffer: 2 x 32 KB. B-staging reuses sA[1] in the prologue.
    __shared__ __align__(16) char sA[2][32768];
    __shared__ float sRed[2][4][32][4];
    __shared__ int   sIdxF[NBLK];
    __shared__ int   sCand[NBLK][2];

    const int t    = threadIdx.x;
    const int lane = t & 63;
    const int w    = t >> 6;
    const int ktl  = w & 3;
    const int nt   = w >> 2;
    const int base_n = blockIdx.x * NBLK;

    // ---- issue A(group 0) -> sA[0] as early as possible (hides L2 latency
    //      under the whole B-staging phase) ----
    {
        const char* gsrc = (const char*)wsA + (w * 4096 + lane * 16);
        char*       ldst = &sA[0][w * 4096];
#pragma unroll
        for (int i = 0; i < 4; ++i)
            gload_lds16(gsrc + i * 1024, ldst + i * 1024);
    }

    // ---- Stage B-fragments (x -> fp16 hi/lo) into sA[1] ----
    {
        half8* sStage = (half8*)sA[1];
        const int nt_s = t >> 8, q = (t >> 6) & 3, l = t & 63;
        const int n_g = base_n + nt_s * 32 + (l & 31);
        const int bb = n_g >> 10, hwv = n_g & 1023;
        const int c0 = q * 16 + (l >> 5) * 8;
        half8 h8, l8;
#pragma unroll
        for (int j = 0; j < 8; ++j) {
            float v = z[bb * CHW + (c0 + j) * HW + hwv];
            _Float16 hh = (_Float16)v;
            _Float16 ll = (_Float16)(v - (float)hh);
            h8[j] = hh; l8[j] = ll;
        }
        sStage[((nt_s * 4 + q) * 2 + 0) * 64 + l] = h8;
        sStage[((nt_s * 4 + q) * 2 + 1) * 64 + l] = l8;
    }
    __syncthreads();     // drains vmcnt(0): A(0) landed in sA[0]; B staged in sA[1]

    half8 b_xh[4], b_xl[4];
    {
        const half8* sStage = (const half8*)sA[1];
#pragma unroll
        for (int q = 0; q < 4; ++q) {
            b_xh[q] = sStage[((nt * 4 + q) * 2 + 0) * 64 + lane];
            b_xl[q] = sStage[((nt * 4 + q) * 2 + 1) * 64 + lane];
        }
    }
    __syncthreads();     // all waves done reading sA[1] -> free for A(1)

    // ---- k-group loop. Per group: issue A(g+1) into buf[(g+1)&1], ds_read
    //      A-frags from buf[g&1], 12 MFMAs, scan with exact-fp32 cn fold.
    //      __syncthreads at the end (= s_waitcnt vmcnt(0) lgkmcnt(0); s_barrier)
    //      guarantees A(g+1) landed; the drain is free because issue->wait
    //      spans the whole MFMA+scan region (~1700 cy >> ~200 cy L2 latency). ----
    float bk0 = -3.4e38f, sk0 = -3.4e38f; int bi0 = 0, si0 = 0;
    float bk1 = -3.4e38f, sk1 = -3.4e38f; int bi1 = 0, si1 = 0;

#pragma unroll
    for (int g = 0; g < NGROUPS; ++g) {
        const int kt = g * 4 + ktl;
        const int b  = g & 1;

        // prefetch next group's A into the other buffer
        if (g + 1 < NGROUPS) {
            const char* gsrc = (const char*)wsA + (g + 1) * 32768 + w * 4096 + lane * 16;
            char*       ldst = &sA[b ^ 1][w * 4096];
#pragma unroll
            for (int i = 0; i < 4; ++i)
                gload_lds16(gsrc + i * 1024, ldst + i * 1024);
        }

        // this group's A-frags from LDS (8 x ds_read_b128, linear, conflict-free)
        half8 a_h[4], a_l[4];
        {
            const char* bp = &sA[b][ktl * 8192 + lane * 16];
#pragma unroll
            for (int q = 0; q < 4; ++q) {
                a_h[q] = *(const half8*)(bp + q * 2048);
                a_l[q] = *(const half8*)(bp + q * 2048 + 1024);
            }
        }

        // cn for this group's 16 rows/lane: broadcast float4 loads from L2
        float cnf[16];
        {
            const float4* cp4 = (const float4*)(wsCn + kt * 32 + 4 * (lane >> 5));
            float4 cA = cp4[0], cB = cp4[2], cC = cp4[4], cD = cp4[6];
            cnf[0]=cA.x; cnf[1]=cA.y; cnf[2]=cA.z; cnf[3]=cA.w;
            cnf[4]=cB.x; cnf[5]=cB.y; cnf[6]=cB.z; cnf[7]=cB.w;
            cnf[8]=cC.x; cnf[9]=cC.y; cnf[10]=cC.z; cnf[11]=cC.w;
            cnf[12]=cD.x; cnf[13]=cD.y; cnf[14]=cD.z; cnf[15]=cD.w;
        }

        f32x16 acc = {};
#pragma unroll
        for (int q = 0; q < 4; ++q) acc = __builtin_amdgcn_mfma_f32_32x32x16_f16(a_h[q], b_xh[q], acc, 0, 0, 0);
#pragma unroll
        for (int q = 0; q < 4; ++q) acc = __builtin_amdgcn_mfma_f32_32x32x16_f16(a_l[q], b_xh[q], acc, 0, 0, 0);
#pragma unroll
        for (int q = 0; q < 4; ++q) acc = __builtin_amdgcn_mfma_f32_32x32x16_f16(a_h[q], b_xl[q], acc, 0, 0, 0);

        const int kbase = kt * 32 + 4 * (lane >> 5);
#pragma unroll
        for (int r = 0; r < 8; ++r) {
            float v = fmaf(-0.5f, cnf[r], acc[r]);      // fold -0.5*||c||^2 (exact fp32)
            int ki = kbase + (r & 3) + 8 * (r >> 2);
            if (v > bk0)      { sk0 = bk0; si0 = bi0; bk0 = v; bi0 = ki; }
            else if (v > sk0) { sk0 = v; si0 = ki; }
        }
#pragma unroll
        for (int r = 8; r < 16; ++r) {
            float v = fmaf(-0.5f, cnf[r], acc[r]);
            int ki = kbase + (r & 3) + 8 * (r >> 2);
            if (v > bk1)      { sk1 = bk1; si1 = bi1; bk1 = v; bi1 = ki; }
            else if (v > sk1) { sk1 = v; si1 = ki; }
        }

        if (g + 1 < NGROUPS) __syncthreads();
    }

    // merge the two chains, then lane halves
    float bk = bk0, sk = sk0; int bi = bi0, si = si0;
    merge2(bk, bi, sk, si, bk1, bi1, sk1, si1);
    {
        float obk = __shfl_xor(bk, 32, 64); int obi = __shfl_xor(bi, 32, 64);
        float osk = __shfl_xor(sk, 32, 64); int osi = __shfl_xor(si, 32, 64);
        merge2(bk, bi, sk, si, obk, obi, osk, osi);
    }
    if (lane < 32) {
        sRed[nt][ktl][lane][0] = bk;
        sRed[nt][ktl][lane][1] = __int_as_float(bi);
        sRed[nt][ktl][lane][2] = sk;
        sRed[nt][ktl][lane][3] = __int_as_float(si);
    }
    __syncthreads();

    // ---- per-n final merge -> candidate pair ----
    if (t < NBLK) {
        const int ntf = t >> 5, col = t & 31;
        float fbk = sRed[ntf][0][col][0]; int fbi = __float_as_int(sRed[ntf][0][col][1]);
        float fsk = sRed[ntf][0][col][2]; int fsi = __float_as_int(sRed[ntf][0][col][3]);
#pragma unroll
        for (int p = 1; p < 4; ++p)
            merge2(fbk, fbi, fsk, fsi,
                   sRed[ntf][p][col][0], __float_as_int(sRed[ntf][p][col][1]),
                   sRed[ntf][p][col][2], __float_as_int(sRed[ntf][p][col][3]));
        sCand[t][0] = fbi; sCand[t][1] = fsi;
    }
    __syncthreads();

    // ---- exact fp32 top-2 refinement, parallel over all 512 threads:
    //      thread = (n 0..63) x (cand 0..1) x (c-chunk 0..3), shfl-reduced ----
    {
        const int n_l = t >> 3, ci = (t >> 2) & 1, ch = t & 3;
        const int k   = sCand[n_l][ci];
        const int n_g = base_n + n_l;
        const int bb  = n_g >> 10, hwv = n_g & 1023;
        const float* zp = z + bb * CHW + hwv;
        float x0[16];
#pragma unroll
        for (int i = 0; i < 16; ++i) x0[i] = zp[(ch * 16 + i) * HW];
        const float4* crow = (const float4*)(cb + k * C_DIM + ch * 16);
        float dot = 0.f, xn = 0.f;
#pragma unroll
        for (int i = 0; i < 4; ++i) {
            float4 f = crow[i];
            dot = fmaf(x0[4*i+0], f.x, dot); xn = fmaf(x0[4*i+0], x0[4*i+0], xn);
            dot = fmaf(x0[4*i+1], f.y, dot); xn = fmaf(x0[4*i+1], x0[4*i+1], xn);
            dot = fmaf(x0[4*i+2], f.z, dot); xn = fmaf(x0[4*i+2], x0[4*i+2], xn);
            dot = fmaf(x0[4*i+3], f.w, dot); xn = fmaf(x0[4*i+3], x0[4*i+3], xn);
        }
        dot += __shfl_xor(dot, 1, 64); dot += __shfl_xor(dot, 2, 64);
        xn  += __shfl_xor(xn, 1, 64);  xn  += __shfl_xor(xn, 2, 64);
        float d   = fmaf(-2.f, dot, xn) + wsCn[k];
        float d_o = __shfl_xor(d, 4, 64);
        int   k_o = __shfl_xor(k, 4, 64);
        if ((t & 7) == 0) {   // ci==0 lane: self = best-cand, other = second-cand
            int win = (d_o < d || (d_o == d && k_o < k)) ? k_o : k;
            sIdxF[n_l] = win;
            out[CODES_ELEMS + n_g] = (float)win;
        }
    }
    __syncthreads();

    // ---- codes write ----
    {
        const int c_hi = t >> 6, nl = t & 63;
        const int idx = sIdxF[nl];
        const int n_g = base_n + nl;
        const int bb = n_g >> 10, hwv = n_g & 1023;
#pragma unroll
        for (int j = 0; j < 8; ++j) {
            const int c = c_hi * 8 + j;
            out[bb * CHW + c * HW + hwv] = cb[idx * C_DIM + c];
        }
    }
}

extern "C" void kernel_launch(void* const* d_in, const int* in_sizes, int n_in,
                              void* d_out, int out_size, void* d_ws, size_t ws_size,
                              hipStream_t stream) {
    const float* z  = (const float*)d_in[0];
    const float* cb = (const float*)d_in[1];
    float* out = (float*)d_out;
    half8* wsA  = (half8*)d_ws;
    float* wsCn = (float*)((char*)d_ws + WS_A_ELEMS * sizeof(half8));

    prep_kernel<<<33, 256, 0, stream>>>(cb, wsA, wsCn);
    vq_kernel<<<N_TOTAL / NBLK, THREADS, 0, stream>>>(z, cb, wsA, wsCn, out);
}